// Round 1
// baseline (70.008 us; speedup 1.0000x reference)
//
#include <hip/hip_runtime.h>
#include <math.h>

#ifndef M_PI
#define M_PI 3.14159265358979323846
#endif

// N=2048 particles. Pair sum over i!=j with weight 0.5 (symmetry folds the
// tril-masked qq/qu sums and the explicit 0.5 on the uu term into one scale).
constexpr int N_ATOMS = 2048;
constexpr int BLOCK   = 256;
constexpr int JT      = 32;                  // j-tile per block
constexpr int GRID_I  = N_ATOMS / BLOCK;     // 8
constexpr int GRID_J  = N_ATOMS / JT;        // 64
constexpr int NPART   = GRID_I * GRID_J;     // 512 partial sums

__global__ __launch_bounds__(BLOCK) void ewald_pairs(
    const float* __restrict__ q, const float* __restrict__ r,
    const float* __restrict__ u, float* __restrict__ partial)
{
    __shared__ float sq[JT], srx[JT], sry[JT], srz[JT], sux[JT], suy[JT], suz[JT];
    __shared__ float swave[BLOCK / 64];

    const int tid = threadIdx.x;
    const int i   = blockIdx.x * BLOCK + tid;   // one i per thread
    const int j0  = blockIdx.y * JT;

    if (tid < JT) {
        const int j = j0 + tid;
        sq[tid]  = q[j];
        srx[tid] = r[3 * j + 0]; sry[tid] = r[3 * j + 1]; srz[tid] = r[3 * j + 2];
        sux[tid] = u[3 * j + 0]; suy[tid] = u[3 * j + 1]; suz[tid] = u[3 * j + 2];
    }
    __syncthreads();

    const float qi  = q[i];
    const float rix = r[3 * i + 0], riy = r[3 * i + 1], riz = r[3 * i + 2];
    const float uix = u[3 * i + 0], uiy = u[3 * i + 1], uiz = u[3 * i + 2];

    const float A = 0.70710678118654752f;   // a = 1/(sigma*sqrt(2)), sigma=1
    const float C = 0.79788456080286536f;   // 2a/sqrt(pi); note 2*a*a*C == C

    float acc = 0.0f;

#pragma unroll 8
    for (int jj = 0; jj < JT; ++jj) {
        const int   j  = j0 + jj;
        const float dx = srx[jj] - rix;      // r_j - r_i (matches reference r_ij)
        const float dy = sry[jj] - riy;
        const float dz = srz[jj] - riz;
        float rsq = dx * dx + dy * dy + dz * dz;
        const bool diag = (j == i);
        rsq = diag ? 1.0f : rsq;             // keep math finite on the diagonal

        const float rinv  = __builtin_amdgcn_rsqf(rsq);   // v_rsq_f32
        const float rn    = rsq * rinv;
        const float erfv  = erff(A * rn);
        const float g     = __expf(-0.5f * rsq);          // exp(-(a*rn)^2)
        const float rinv2 = rinv * rinv;
        const float er3   = erfv * rinv2 * rinv;          // erf/r^3
        const float cg2   = C * g * rinv2;                // c*gauss/r^2
        const float s1    = er3 - cg2;
        const float s2    = 3.0f * er3 - 2.0f * cg2 - C * g;  // 2*a*a*c == c

        const float ujx = sux[jj], ujy = suy[jj], ujz = suz[jj];
        const float uid  = uix * dx + uiy * dy + uiz * dz;
        const float ujd  = ujx * dx + ujy * dy + ujz * dz;
        const float uiuj = uix * ujx + uiy * ujy + uiz * ujz;
        const float qj   = sq[jj];

        // qq: q_i q_j erf/r
        // qu: (u_i·f)q_j - q_i(f·u_j) with f = -s1*d  ->  -s1*(uid*qj - qi*ujd)
        // uu: -(s2*rinv^2*uid*ujd - s1*uiuj)
        float t = qi * qj * erfv * rinv
                - s1 * (uid * qj - qi * ujd)
                - (s2 * rinv2 * uid * ujd - s1 * uiuj);
        acc += diag ? 0.0f : t;
    }

    // wave(64) shuffle reduce -> per-wave LDS -> block sum
    for (int off = 32; off > 0; off >>= 1)
        acc += __shfl_down(acc, off, 64);
    const int lane = tid & 63, wave = tid >> 6;
    if (lane == 0) swave[wave] = acc;
    __syncthreads();
    if (tid == 0) {
        float s = 0.0f;
        for (int w = 0; w < BLOCK / 64; ++w) s += swave[w];
        partial[blockIdx.y * gridDim.x + blockIdx.x] = s;
    }
}

__global__ __launch_bounds__(256) void ewald_reduce(
    const float* __restrict__ partial, float* __restrict__ out)
{
    __shared__ float swave[4];
    float v = 0.0f;
    for (int k = threadIdx.x; k < NPART; k += 256) v += partial[k];
    for (int off = 32; off > 0; off >>= 1)
        v += __shfl_down(v, off, 64);
    const int lane = threadIdx.x & 63, wave = threadIdx.x >> 6;
    if (lane == 0) swave[wave] = v;
    __syncthreads();
    if (threadIdx.x == 0) {
        const float SCALE = (float)(0.5 * 90.0474 / (2.0 * M_PI));
        out[0] = (swave[0] + swave[1] + swave[2] + swave[3]) * SCALE;
    }
}

extern "C" void kernel_launch(void* const* d_in, const int* in_sizes, int n_in,
                              void* d_out, int out_size, void* d_ws, size_t ws_size,
                              hipStream_t stream) {
    const float* q = (const float*)d_in[0];   // (2048,)
    const float* r = (const float*)d_in[1];   // (2048,3)
    const float* u = (const float*)d_in[2];   // (2048,3)
    float* partial = (float*)d_ws;            // 512 floats of scratch

    dim3 grid(GRID_I, GRID_J);
    ewald_pairs<<<grid, BLOCK, 0, stream>>>(q, r, u, partial);
    ewald_reduce<<<1, 256, 0, stream>>>(partial, (float*)d_out);
}

// Round 2
// 68.515 us; speedup vs baseline: 1.0218x; 1.0218x over previous
//
#include <hip/hip_runtime.h>
#include <math.h>

#ifndef M_PI
#define M_PI 3.14159265358979323846
#endif

// N=2048. Sum over unordered pairs i>j only (the per-pair term is symmetric
// under i<->j: d flips sign, uid <-> -ujd, so qq/qu/uu are all invariant).
// Reference's tril qq/qu sums count each unordered pair once; the uu term's
// explicit 0.5 x full-matrix also equals once-per-unordered-pair. So:
//   pot = (NORM/2pi) * sum_{i>j} t_ij
constexpr int N_ATOMS = 2048;
constexpr int BLOCK   = 64;               // one wave per block
constexpr int ICH     = 64;               // i-chunk per block
constexpr int JT      = 32;               // j-tile per block
constexpr int GI      = N_ATOMS / ICH;    // 32
constexpr int GJ      = N_ATOMS / JT;     // 64
constexpr int NPART   = GI * GJ;          // 2048 partial slots (8 KB of d_ws)

__global__ __launch_bounds__(BLOCK) void ewald_pairs(
    const float* __restrict__ q, const float* __restrict__ r,
    const float* __restrict__ u, float* __restrict__ partial)
{
    const int bi  = blockIdx.x, bj = blockIdx.y;
    const int pid = bi * GJ + bj;

    // block has work iff exists (i,j) with j<i: 32*bj < 64*bi+63  =>  bj <= 2*bi+1
    if (bj > 2 * bi + 1) {
        if (threadIdx.x == 0) partial[pid] = 0.0f;   // deterministic empty slot
        return;
    }

    const int i  = bi * ICH + threadIdx.x;
    const int j0 = bj * JT;

    const float qi  = q[i];
    const float rix = r[3 * i + 0], riy = r[3 * i + 1], riz = r[3 * i + 2];
    const float uix = u[3 * i + 0], uiy = u[3 * i + 1], uiz = u[3 * i + 2];

    const float C  = 0.79788456080286536f;  // 2a/sqrt(pi), a=1/sqrt(2); 2a^2*C == C
    const float PA = 0.23166036f;           // p * a, p = 0.3275911 (A&S 7.1.26)
    const float A1 = 0.254829592f, A2 = -0.284496736f, A3 = 1.421413741f;
    const float A4 = -1.453152027f, A5 = 1.061405429f;

    float acc = 0.0f;

#pragma unroll 8
    for (int jj = 0; jj < JT; ++jj) {
        const int j = j0 + jj;              // wave-uniform -> scalar loads
        const float qj  = q[j];
        const float rjx = r[3 * j + 0], rjy = r[3 * j + 1], rjz = r[3 * j + 2];
        const float ujx = u[3 * j + 0], ujy = u[3 * j + 1], ujz = u[3 * j + 2];

        const float dx = rjx - rix, dy = rjy - riy, dz = rjz - riz;  // r_j - r_i
        const float rsq = dx * dx + dy * dy + dz * dz;

        const float rinv = __builtin_amdgcn_rsqf(rsq);   // NaN path on diag is masked below
        const float rn   = rsq * rinv;
        const float g    = __expf(-0.5f * rsq);          // exp(-(a*rn)^2)

        // A&S 7.1.26: erf(x) = 1 - (a1 t + ... + a5 t^5) e^{-x^2}, t = 1/(1+p*x)
        const float t5 = __builtin_amdgcn_rcpf(fmaf(PA, rn, 1.0f));
        const float poly = t5 * fmaf(t5, fmaf(t5, fmaf(t5, fmaf(t5, A5, A4), A3), A2), A1);
        const float erfv = 1.0f - poly * g;

        const float rinv2 = rinv * rinv;
        const float er3   = erfv * rinv2 * rinv;
        const float Cg    = C * g;
        const float cg2   = Cg * rinv2;
        const float s1    = er3 - cg2;                         // erf/r^3 - c g/r^2
        const float s2    = fmaf(3.0f, er3, -2.0f * cg2) - Cg; // + uses 2a^2 c == c

        const float uid  = uix * dx + uiy * dy + uiz * dz;
        const float ujd  = ujx * dx + ujy * dy + ujz * dz;
        const float uiuj = uix * ujx + uiy * ujy + uiz * ujz;

        const float t = qi * qj * erfv * rinv
                      - s1 * (uid * qj - qi * ujd)
                      - (s2 * rinv2 * uid * ujd - s1 * uiuj);

        acc += (j < i) ? t : 0.0f;          // excludes diagonal & upper triangle
    }

    for (int off = 32; off > 0; off >>= 1)
        acc += __shfl_down(acc, off, 64);
    if (threadIdx.x == 0) partial[pid] = acc;
}

__global__ __launch_bounds__(256) void ewald_reduce(
    const float* __restrict__ partial, float* __restrict__ out)
{
    __shared__ float swave[4];
    float v = 0.0f;
    for (int k = threadIdx.x; k < NPART; k += 256) v += partial[k];
    for (int off = 32; off > 0; off >>= 1)
        v += __shfl_down(v, off, 64);
    if ((threadIdx.x & 63) == 0) swave[threadIdx.x >> 6] = v;
    __syncthreads();
    if (threadIdx.x == 0) {
        const float SCALE = (float)(90.0474 / (2.0 * M_PI));  // pairs counted once
        out[0] = (swave[0] + swave[1] + swave[2] + swave[3]) * SCALE;
    }
}

extern "C" void kernel_launch(void* const* d_in, const int* in_sizes, int n_in,
                              void* d_out, int out_size, void* d_ws, size_t ws_size,
                              hipStream_t stream) {
    const float* q = (const float*)d_in[0];   // (2048,)
    const float* r = (const float*)d_in[1];   // (2048,3)
    const float* u = (const float*)d_in[2];   // (2048,3)
    float* partial = (float*)d_ws;            // NPART floats

    dim3 grid(GI, GJ);
    ewald_pairs<<<grid, BLOCK, 0, stream>>>(q, r, u, partial);
    ewald_reduce<<<1, 256, 0, stream>>>(partial, (float*)d_out);
}